// Round 1
// 877.150 us; speedup vs baseline: 1.1551x; 1.1551x over previous
//
#include <hip/hip_runtime.h>
#include <hip/hip_bf16.h>
#include <stdint.h>

using u16 = unsigned short;
using u32 = unsigned int;

typedef __attribute__((ext_vector_type(8))) short short8;
typedef __attribute__((ext_vector_type(4))) float floatx4;

__device__ __forceinline__ u16 f2bf(float f) {
  __hip_bfloat16 h = __float2bfloat16(f);
  return *reinterpret_cast<u16*>(&h);
}

__device__ __forceinline__ void gl_lds16(const void* g, void* l) {
  __builtin_amdgcn_global_load_lds((const __attribute__((address_space(1))) void*)g,
                                   (__attribute__((address_space(3))) void*)l, 16, 0, 0);
}

// ---------------- transpose fp32 [R][Cc] -> bf16 [Cc][R] ----------------
__global__ __launch_bounds__(256)
void transpose_to_bf16(const float* __restrict__ in, u16* __restrict__ out,
                       int R, int Cc) {
  __shared__ float tile[32][33];
  int c0 = blockIdx.x * 32;
  int r0 = blockIdx.y * 32;
  int tx = threadIdx.x;   // 0..31
  int ty = threadIdx.y;   // 0..7
#pragma unroll
  for (int i = 0; i < 32; i += 8)
    tile[ty + i][tx] = in[(size_t)(r0 + ty + i) * Cc + c0 + tx];
  __syncthreads();
#pragma unroll
  for (int i = 0; i < 32; i += 8)
    out[(size_t)(c0 + ty + i) * R + r0 + tx] = f2bf(tile[tx][ty + i]);
}

// ---------------- elementwise fp32 -> bf16 ----------------
__global__ __launch_bounds__(256)
void cvt_bf16(const float4* __restrict__ in, uint2* __restrict__ out, int n4) {
  int i = blockIdx.x * 256 + threadIdx.x;
  if (i >= n4) return;
  float4 v = in[i];
  u32 lo = (u32)f2bf(v.x) | ((u32)f2bf(v.y) << 16);
  u32 hi = (u32)f2bf(v.z) | ((u32)f2bf(v.w) << 16);
  out[i] = make_uint2(lo, hi);
}

// ---------------- legacy GEMM (fp32-A fallback only) ----------------
constexpr int BM = 128, BN = 128, BK = 32;

template <bool A_BF16, bool RELU>
__global__ __launch_bounds__(256, 3)
void gemm_bt(const void* __restrict__ Aip, const u16* __restrict__ BT,
             const float* __restrict__ bias, u16* __restrict__ C,
             int M, int N, int K) {
  __shared__ __align__(16) u16 As[BM * BK];
  __shared__ __align__(16) u16 Bs[BN * BK];
  const int tid  = threadIdx.x;
  const int lane = tid & 63;
  const int wave = tid >> 6;
  const int m0 = blockIdx.y * BM;
  const int n0 = blockIdx.x * BN;
  const int wm = (wave & 1) * 64;
  const int wn = (wave >> 1) * 64;
  const int row = lane & 15;
  const int kq  = lane >> 4;

  floatx4 acc[4][4] = {};

  int a_off[4], b_off[4];
#pragma unroll
  for (int t = 0; t < 4; ++t) {
    int mr = wm + t * 16 + row;
    a_off[t] = mr * BK + ((kq ^ ((mr >> 1) & 3)) * 8);
    int nr = wn + t * 16 + row;
    b_off[t] = nr * BK + ((kq ^ ((nr >> 1) & 3)) * 8);
  }

  const u16* bptr[2];
  int b_lds[2];
#pragma unroll
  for (int it = 0; it < 2; ++it) {
    int c = it * 256 + tid;
    int nrow = c >> 2;
    int kc = ((c & 3) ^ ((nrow >> 1) & 3)) * 8;
    bptr[it] = BT + (size_t)(n0 + nrow) * K + kc;
    b_lds[it] = (it * 256 + wave * 64) * 8;
  }

  const u16* aptrB[2];
  int a_ldsB[2];
  const float* aptrF[4];
  int a_stF[4];
  if constexpr (A_BF16) {
    const u16* A = (const u16*)Aip;
#pragma unroll
    for (int it = 0; it < 2; ++it) {
      int c = it * 256 + tid;
      int mrow = c >> 2;
      int kc = ((c & 3) ^ ((mrow >> 1) & 3)) * 8;
      aptrB[it] = A + (size_t)(m0 + mrow) * K + kc;
      a_ldsB[it] = (it * 256 + wave * 64) * 8;
    }
  } else {
    const float* A = (const float*)Aip;
#pragma unroll
    for (int it = 0; it < 4; ++it) {
      int idx = it * 256 + tid;
      int mrow = idx >> 3;
      int kc = (idx & 7) * 4;
      aptrF[it] = A + (size_t)(m0 + mrow) * K + kc;
      int chunk = kc >> 3, half = (kc >> 2) & 1;
      int sc = chunk ^ ((mrow >> 1) & 3);
      a_stF[it] = mrow * BK + sc * 8 + half * 4;
    }
  }

  for (int k0 = 0; k0 < K; k0 += BK) {
    __syncthreads();
    if constexpr (A_BF16) {
#pragma unroll
      for (int it = 0; it < 2; ++it)
        gl_lds16(aptrB[it] + k0, &As[a_ldsB[it]]);
    } else {
#pragma unroll
      for (int it = 0; it < 4; ++it) {
        float4 v = *(const float4*)(aptrF[it] + k0);
        u32 lo = (u32)f2bf(v.x) | ((u32)f2bf(v.y) << 16);
        u32 hi = (u32)f2bf(v.z) | ((u32)f2bf(v.w) << 16);
        *(uint2*)&As[a_stF[it]] = make_uint2(lo, hi);
      }
    }
#pragma unroll
    for (int it = 0; it < 2; ++it)
      gl_lds16(bptr[it] + k0, &Bs[b_lds[it]]);
    __syncthreads();

    short8 a[4], b[4];
#pragma unroll
    for (int t = 0; t < 4; ++t) {
      a[t] = *(const short8*)&As[a_off[t]];
      b[t] = *(const short8*)&Bs[b_off[t]];
    }
#pragma unroll
    for (int mt = 0; mt < 4; ++mt)
#pragma unroll
      for (int nt = 0; nt < 4; ++nt)
        acc[mt][nt] = __builtin_amdgcn_mfma_f32_16x16x32_bf16(
            a[mt], b[nt], acc[mt][nt], 0, 0, 0);
  }

  const int ccol = row;
  const int crow = kq * 4;
#pragma unroll
  for (int mt = 0; mt < 4; ++mt) {
#pragma unroll
    for (int nt = 0; nt < 4; ++nt) {
      int gm = m0 + wm + mt * 16 + crow;
      int gn = n0 + wn + nt * 16 + ccol;
      float bv = bias[gn];
#pragma unroll
      for (int r = 0; r < 4; ++r) {
        float v = acc[mt][nt][r] + bv;
        if (RELU) v = fmaxf(v, 0.f);
        C[(size_t)(gm + r) * N + gn] = f2bf(v);
      }
    }
  }
}

// ======================================================================
// gemm256: BM=256 x BN=128, BK=64, 512 threads (8 waves = 4M x 2N),
// triple-buffered LDS (144 KiB), counted-vmcnt phase schedule (T3+T4),
// setprio around MFMA clusters (T5), XOR chunk swizzle (T2-style, 2-way),
// XCD-aware block swizzle (T1). Grid must be dim3(8, M/256).
// ======================================================================
constexpr int A_BUF  = 256 * 64;      // u16 per A buffer (32 KiB)
constexpr int B_BUF  = 128 * 64;      // u16 per B buffer (16 KiB)
constexpr int B_BASE = 3 * A_BUF;     // B region starts after 3 A buffers
constexpr int LDS_BYTES = (3 * A_BUF + 3 * B_BUF) * 2;  // 147456

#define MM(i, j, va, vb) \
  acc[i][j] = __builtin_amdgcn_mfma_f32_16x16x32_bf16(va, vb, acc[i][j], 0, 0, 0)
#define MEMF() asm volatile("" ::: "memory")
#define BAR() do { MEMF(); __builtin_amdgcn_s_barrier(); MEMF(); } while (0)
#define STAGE_AH(h, bufo) \
  do { gl_lds16(apt[h][0], lds + (bufo) + adst[h][0]); apt[h][0] += 64; \
       gl_lds16(apt[h][1], lds + (bufo) + adst[h][1]); apt[h][1] += 64; } while (0)
#define STAGE_BH(h, bufo) \
  do { gl_lds16(bpt[h], lds + (bufo) + bdst[h]); bpt[h] += 64; } while (0)

template <bool RELU>
__global__ __launch_bounds__(512, 2)
void gemm256(const u16* __restrict__ A, const u16* __restrict__ BT,
             const float* __restrict__ bias, u16* __restrict__ C,
             int N, int K) {
  extern __shared__ u16 lds[];
  const int tid  = threadIdx.x;
  const int lane = tid & 63;
  const int wave = tid >> 6;
  const int wm = wave >> 1;       // 0..3  (64-row strip of A)
  const int wn = wave & 1;        // 0..1  (64-col strip of B)
  const int row = lane & 15;
  const int kq  = lane >> 4;
  const int sw  = lane & 7;

  // XCD swizzle: grid is 8 x 32 = 256 blocks; give each XCD 4 full A-row
  // strips (all 8 n-blocks) so A is reused 8x inside one L2.
  const int orig = blockIdx.y * 8 + blockIdx.x;
  const int rr = ((orig & 7) << 5) | (orig >> 3);
  const int n0 = (rr & 7) * 128;
  const int m0 = (rr >> 3) * 256;

  // fragment read offsets (u16 units, buffer-relative).
  // LDS slot (row, c) holds global chunk (row, c ^ (row&7)); reader XORs back.
  const int o0 = ((kq) ^ sw) * 8;        // ksub 0: chunk kq
  const int o1 = ((4 | kq) ^ sw) * 8;    // ksub 1: chunk 4+kq
  const int ar0 = (wm * 64 + row) * 64;
  const int ar1 = ar0 + 16 * 64;
  const int ar2 = ar0 + 32 * 64;
  const int ar3 = ar0 + 48 * 64;
  const int br0 = (wn * 64 + row) * 64;
  const int br1 = br0 + 16 * 64;
  const int br2 = br0 + 32 * 64;
  const int br3 = br0 + 48 * 64;

  // staging: A tile = 256x64 bf16 = 2048 chunks of 16B, 2 halves x 2 loads/thread
  //          B tile = 128x64 bf16 = 1024 chunks, 2 halves x 1 load/thread
  // global source pre-swizzled, LDS dest linear (rule: both-sides-or-neither).
  const u16* apt[2][2];
  int adst[2][2];
#pragma unroll
  for (int h = 0; h < 2; ++h)
#pragma unroll
    for (int L = 0; L < 2; ++L) {
      int i = L * 512 + tid;
      int rg = h * 128 + (i >> 3);
      int c = i & 7;
      apt[h][L] = A + (size_t)(m0 + rg) * K + ((c ^ (rg & 7)) * 8);
      adst[h][L] = h * 8192 + L * 4096 + wave * 512;
    }
  const u16* bpt[2];
  int bdst[2];
#pragma unroll
  for (int h = 0; h < 2; ++h) {
    int rg = h * 64 + (tid >> 3);
    int c = tid & 7;
    bpt[h] = BT + (size_t)(n0 + rg) * K + ((c ^ (rg & 7)) * 8);
    bdst[h] = B_BASE + h * 4096 + wave * 512;
  }

  // prologue: stage tile 0 -> buf0, tile 1 -> buf1 (12 loads/thread in flight)
  STAGE_AH(0, 0);      STAGE_AH(1, 0);      STAGE_BH(0, 0);     STAGE_BH(1, 0);
  STAGE_AH(0, A_BUF);  STAGE_AH(1, A_BUF);  STAGE_BH(0, B_BUF); STAGE_BH(1, B_BUF);
  asm volatile("s_waitcnt vmcnt(6)" ::: "memory");  // tile 0 landed
  BAR();

  floatx4 acc[4][4] = {};
  int cb = 0, sb = 2;
  const int NT = K >> 6;
  for (int T = 0; T < NT; ++T) {
    const bool st = (T + 2 < NT);
    const u16* Ac = lds + cb * A_BUF;
    const u16* Bc = lds + B_BASE + cb * B_BUF;
    const int sA = sb * A_BUF;
    const int sB = sb * B_BUF;

    short8 a0k0, a0k1, a1k0, a1k1, a2k0, a2k1, a3k0, a3k1;
    short8 b0k0, b0k1, b1k0, b1k1, b2k0, b2k1, b3k0, b3k1;

    // ---- P0: read a0,a1,b0,b1 | stage A-half0(T+2) | 8 MFMA ----
    a0k0 = *(const short8*)(Ac + ar0 + o0);
    a0k1 = *(const short8*)(Ac + ar0 + o1);
    a1k0 = *(const short8*)(Ac + ar1 + o0);
    a1k1 = *(const short8*)(Ac + ar1 + o1);
    b0k0 = *(const short8*)(Bc + br0 + o0);
    b0k1 = *(const short8*)(Bc + br0 + o1);
    b1k0 = *(const short8*)(Bc + br1 + o0);
    b1k1 = *(const short8*)(Bc + br1 + o1);
    if (st) STAGE_AH(0, sA);
    BAR();
    __builtin_amdgcn_s_setprio(1);
    MM(0, 0, a0k0, b0k0); MM(0, 1, a0k0, b1k0);
    MM(1, 0, a1k0, b0k0); MM(1, 1, a1k0, b1k0);
    MM(0, 0, a0k1, b0k1); MM(0, 1, a0k1, b1k1);
    MM(1, 0, a1k1, b0k1); MM(1, 1, a1k1, b1k1);
    __builtin_amdgcn_s_setprio(0);
    BAR();

    // ---- P1: read b2,b3 | stage A-half1(T+2) | 8 MFMA ----
    b2k0 = *(const short8*)(Bc + br2 + o0);
    b2k1 = *(const short8*)(Bc + br2 + o1);
    b3k0 = *(const short8*)(Bc + br3 + o0);
    b3k1 = *(const short8*)(Bc + br3 + o1);
    if (st) STAGE_AH(1, sA);
    BAR();
    __builtin_amdgcn_s_setprio(1);
    MM(0, 2, a0k0, b2k0); MM(0, 3, a0k0, b3k0);
    MM(1, 2, a1k0, b2k0); MM(1, 3, a1k0, b3k0);
    MM(0, 2, a0k1, b2k1); MM(0, 3, a0k1, b3k1);
    MM(1, 2, a1k1, b2k1); MM(1, 3, a1k1, b3k1);
    __builtin_amdgcn_s_setprio(0);
    BAR();

    // ---- P2: read a2,a3 | stage B-half0(T+2) | 8 MFMA ----
    a2k0 = *(const short8*)(Ac + ar2 + o0);
    a2k1 = *(const short8*)(Ac + ar2 + o1);
    a3k0 = *(const short8*)(Ac + ar3 + o0);
    a3k1 = *(const short8*)(Ac + ar3 + o1);
    if (st) STAGE_BH(0, sB);
    BAR();
    __builtin_amdgcn_s_setprio(1);
    MM(2, 2, a2k0, b2k0); MM(2, 3, a2k0, b3k0);
    MM(3, 2, a3k0, b2k0); MM(3, 3, a3k0, b3k0);
    MM(2, 2, a2k1, b2k1); MM(2, 3, a2k1, b3k1);
    MM(3, 2, a3k1, b2k1); MM(3, 3, a3k1, b3k1);
    __builtin_amdgcn_s_setprio(0);
    BAR();

    // ---- P3: stage B-half1(T+2) | 8 MFMA | counted vmcnt ----
    if (st) STAGE_BH(1, sB);
    BAR();
    __builtin_amdgcn_s_setprio(1);
    MM(2, 0, a2k0, b0k0); MM(2, 1, a2k0, b1k0);
    MM(3, 0, a3k0, b0k0); MM(3, 1, a3k0, b1k0);
    MM(2, 0, a2k1, b0k1); MM(2, 1, a2k1, b1k1);
    MM(3, 0, a3k1, b0k1); MM(3, 1, a3k1, b1k1);
    __builtin_amdgcn_s_setprio(0);
    // tile T+1 must be landed; keep T+2's 6 loads in flight (never drain to 0
    // in steady state).
    if (st) asm volatile("s_waitcnt vmcnt(6)" ::: "memory");
    else    asm volatile("s_waitcnt vmcnt(0)" ::: "memory");
    BAR();

    cb = (cb == 2) ? 0 : cb + 1;
    sb = (sb == 2) ? 0 : sb + 1;
  }

  // epilogue: C/D layout col=lane&15, row=(lane>>4)*4+r
#pragma unroll
  for (int mt = 0; mt < 4; ++mt) {
#pragma unroll
    for (int nt = 0; nt < 4; ++nt) {
      int gm = m0 + wm * 64 + mt * 16 + kq * 4;
      int gn = n0 + wn * 64 + nt * 16 + row;
      float bv = bias[gn];
#pragma unroll
      for (int r = 0; r < 4; ++r) {
        float v = acc[mt][nt][r] + bv;
        if (RELU) v = fmaxf(v, 0.f);
        C[(size_t)(gm + r) * N + gn] = f2bf(v);
      }
    }
  }
}

// ---------------- heads: one wave per row ----------------
__device__ __forceinline__ float wave_sum(float v) {
#pragma unroll
  for (int m = 32; m >= 1; m >>= 1) v += __shfl_xor(v, m, 64);
  return v;
}

__global__ __launch_bounds__(64)
void head_kernel(const u16* __restrict__ H, const float* __restrict__ Wc,
                 const float* __restrict__ bc, const float* __restrict__ Wr,
                 const float* __restrict__ br, float* __restrict__ out) {
  const int rowi = blockIdx.x;
  const int lane = threadIdx.x;
  const u16* h = H + (size_t)rowi * 1024 + lane * 16;
  uint4 p0 = *(const uint4*)h;
  uint4 p1 = *(const uint4*)(h + 8);
  u32 w[8] = {p0.x, p0.y, p0.z, p0.w, p1.x, p1.y, p1.z, p1.w};
  float x[16];
#pragma unroll
  for (int i = 0; i < 8; ++i) {
    union { u32 u; float f; } lo, hi;
    lo.u = w[i] << 16;
    hi.u = w[i] & 0xffff0000u;
    x[2 * i] = lo.f;
    x[2 * i + 1] = hi.f;
  }
  float ac[4] = {};
  float ar[12] = {};
  const int kbase = lane * 16;
#pragma unroll
  for (int j = 0; j < 16; ++j) {
    float xv = x[j];
    const float* wc = Wc + (size_t)(kbase + j) * 4;
#pragma unroll
    for (int c = 0; c < 4; ++c) ac[c] = fmaf(xv, wc[c], ac[c]);
    const float* wr = Wr + (size_t)(kbase + j) * 12;
#pragma unroll
    for (int r = 0; r < 12; ++r) ar[r] = fmaf(xv, wr[r], ar[r]);
  }
#pragma unroll
  for (int c = 0; c < 4; ++c) ac[c] = wave_sum(ac[c]);
#pragma unroll
  for (int r = 0; r < 12; ++r) ar[r] = wave_sum(ar[r]);

  if (lane == 0) {
    float lg[4], mx = -1e30f;
#pragma unroll
    for (int c = 0; c < 4; ++c) { lg[c] = ac[c] + bc[c]; mx = fmaxf(mx, lg[c]); }
    float s = 0.f;
#pragma unroll
    for (int c = 0; c < 4; ++c) { lg[c] = __expf(lg[c] - mx); s += lg[c]; }
    float inv = 1.f / s;
#pragma unroll
    for (int c = 0; c < 4; ++c) out[(size_t)rowi * 4 + c] = lg[c] * inv;
    float* ob = out + 8192 * 4;
#pragma unroll
    for (int r = 0; r < 12; ++r) ob[(size_t)rowi * 12 + r] = ar[r] + br[r];
  }
}

extern "C" void kernel_launch(void* const* d_in, const int* in_sizes, int n_in,
                              void* d_out, int out_size, void* d_ws, size_t ws_size,
                              hipStream_t stream) {
  const float* X  = (const float*)d_in[0];
  const float* W1 = (const float*)d_in[1];
  const float* b1 = (const float*)d_in[2];
  const float* W2 = (const float*)d_in[3];
  const float* b2 = (const float*)d_in[4];
  const float* Wc = (const float*)d_in[5];
  const float* bc = (const float*)d_in[6];
  const float* Wr = (const float*)d_in[7];
  const float* br = (const float*)d_in[8];

  constexpr int NP = 8192, DIN = 12544, HID = 1024;
  char* ws = (char*)d_ws;
  u16* W1T = (u16*)ws;                                        // HID*DIN bf16
  u16* W2T = (u16*)(ws + (size_t)HID * DIN * 2);              // HID*HID
  u16* H1  = (u16*)((char*)W2T + (size_t)HID * HID * 2);      // NP*HID
  u16* Hb  = H1 + (size_t)NP * HID;                           // NP*HID
  u16* Xb  = Hb + (size_t)NP * HID;                           // NP*DIN (optional)
  size_t need_base = (size_t)HID * DIN * 2 + (size_t)HID * HID * 2 +
                     2 * (size_t)NP * HID * 2;
  bool use_xbf = ws_size >= need_base + (size_t)NP * DIN * 2;

  static bool s_attr = false;
  if (!s_attr) {
    hipFuncSetAttribute(reinterpret_cast<const void*>(gemm256<false>),
                        hipFuncAttributeMaxDynamicSharedMemorySize, LDS_BYTES);
    hipFuncSetAttribute(reinterpret_cast<const void*>(gemm256<true>),
                        hipFuncAttributeMaxDynamicSharedMemorySize, LDS_BYTES);
    s_attr = true;
  }

  transpose_to_bf16<<<dim3(HID / 32, DIN / 32), dim3(32, 8), 0, stream>>>(W1, W1T, DIN, HID);
  transpose_to_bf16<<<dim3(HID / 32, HID / 32), dim3(32, 8), 0, stream>>>(W2, W2T, HID, HID);

  if (use_xbf) {
    int n4 = NP * DIN / 4;
    cvt_bf16<<<(n4 + 255) / 256, 256, 0, stream>>>((const float4*)X, (uint2*)Xb, n4);
    gemm256<false><<<dim3(8, NP / 256), 512, LDS_BYTES, stream>>>(
        Xb, W1T, b1, H1, HID, DIN);
  } else {
    gemm_bt<false, false><<<dim3(HID / BN, NP / BM), 256, 0, stream>>>(
        X, W1T, b1, H1, NP, HID, DIN);
  }
  gemm256<true><<<dim3(8, NP / 256), 512, LDS_BYTES, stream>>>(
      H1, W2T, b2, Hb, HID, HID);
  head_kernel<<<NP, 64, 0, stream>>>(Hb, Wc, bc, Wr, br, (float*)d_out);
}